// Round 4
// baseline (40562.869 us; speedup 1.0000x reference)
//
#include <hip/hip_runtime.h>
#include <hip/hip_bf16.h>

// PK1Block: B=2 S=2048 DIM=2048 NH=16 NKV=4 HD=128 NE=8 TOPK=2 HID=SHID=1024
// External dtype detected at runtime (evidence: fp32 — threshold is 2% of ref
// absmax, and fp32-as-bf16 misreads explain the R0/R2 NaN->OOB aborts).
// ALL internal math/staging is fp32: MoE top-2 selection is sensitive to
// ~0.003 logit noise (adjacent top-k gaps ~0.27), so the whole
// x->h->qkv->attn->x1->h2->logits chain must track the np fp32 reference to
// ~1e-6 or ~1% of tokens get misrouted (R3: bf16 staging -> 0.846 absmax).
#define B_    2
#define S_    2048
#define DIM_  2048
#define NH_   16
#define NKV_  4
#define HD_   128
#define NE_   8
#define HID_  1024
#define T_    (B_*S_)          // 4096 tokens

typedef unsigned short u16;    // bf16 bits

#define DT_BF16 1
#define DT_F32  2

template<typename T> struct dtid;
template<> struct dtid<float> { static constexpr int v = DT_F32;  };
template<> struct dtid<u16>   { static constexpr int v = DT_BF16; };

__device__ __forceinline__ float u2f(u16 u) {
    union { unsigned int i; float f; } v; v.i = ((unsigned int)u) << 16; return v.f;
}
__device__ __forceinline__ u16 f2bf(float f) {
    union { float f; unsigned int i; } v; v.f = f;
    unsigned int x = v.i;
    return (u16)((x + 0x7fffu + ((x >> 16) & 1u)) >> 16);   // RNE
}

template<typename T> __device__ __forceinline__ float ldf(const T* p);
template<> __device__ __forceinline__ float ldf<float>(const float* p) { return *p; }
template<> __device__ __forceinline__ float ldf<u16>(const u16* p)     { return u2f(*p); }

template<typename T> __device__ __forceinline__ void stf(T* p, float v);
template<> __device__ __forceinline__ void stf<float>(float* p, float v) { *p = v; }
template<> __device__ __forceinline__ void stf<u16>(u16* p, float v)     { *p = f2bf(v); }

template<typename T> __device__ __forceinline__ float4 ld4(const T* p);
template<> __device__ __forceinline__ float4 ld4<float>(const float* p) {
    return *(const float4*)p;
}
template<> __device__ __forceinline__ float4 ld4<u16>(const u16* p) {
    ushort4 q = *(const ushort4*)p;
    return make_float4(u2f(q.x), u2f(q.y), u2f(q.z), u2f(q.w));
}

// ---------------------------------------------------------------- dtype detect
__global__ void detect_kernel(const unsigned int* __restrict__ fcos_words,
                              int* __restrict__ flag)
{
    // freqs_cos row 0 = cos(0) = 1.0 repeated. fp32 word0 = 0x3F800000;
    // bf16 word0 = 0x3F803F80.
    *flag = (fcos_words[0] == 0x3F800000u) ? DT_F32 : DT_BF16;
}

// ------------------------------------------------- RMSNorm: IT in -> fp32 out
template<typename IT, typename WT>
__global__ __launch_bounds__(256) void rmsnorm_kernel(const int* __restrict__ flag,
                                                      const IT* __restrict__ xin,
                                                      const WT* __restrict__ w,
                                                      float* __restrict__ out)
{
    if (*flag != dtid<WT>::v) return;
    int t = blockIdx.x;
    const IT* xb = xin + (size_t)t * DIM_;
    float ss = 0.f;
    for (int d = threadIdx.x; d < DIM_; d += 256) {
        float v = ldf(xb + d);
        ss += v * v;
    }
    #pragma unroll
    for (int o = 32; o > 0; o >>= 1) ss += __shfl_xor(ss, o);
    __shared__ float red[4];
    if ((threadIdx.x & 63) == 0) red[threadIdx.x >> 6] = ss;
    __syncthreads();
    float tot = red[0] + red[1] + red[2] + red[3];
    float inv = rsqrtf(tot * (1.0f / DIM_) + 1e-6f);
    for (int d = threadIdx.x; d < DIM_; d += 256)
        out[(size_t)t * DIM_ + d] = ldf(xb + d) * inv * ldf(w + d);
}

// ---------------------- GEMM: A(fp32 ws) @ B(T) -> CF(fp32) [+resid(T)]
// 64x64 tile, BK=16, 256 threads, 4x4 micro-tile, fp32 accumulate.
template<typename T>
__global__ __launch_bounds__(256) void gemm_kernel(const int* __restrict__ flag,
                                                   const float* __restrict__ A,
                                                   const T* __restrict__ Bw,
                                                   float* __restrict__ CF,
                                                   const T* __restrict__ resid,
                                                   int M, int N, int K)
{
    if (*flag != dtid<T>::v) return;
    __shared__ float As[64][17];   // +1 pad
    __shared__ float Bs[16][64];
    int tid = threadIdx.x;
    int bm = blockIdx.y, bn = blockIdx.x;
    int tx = tid & 15, ty = tid >> 4;

    int ar = tid >> 2;              // 0..63
    int ac = (tid & 3) << 2;        // 0,4,8,12
    int br = tid >> 4;              // 0..15
    int bc = (tid & 15) << 2;       // 0..60

    const float* Ap = A  + (size_t)(bm * 64 + ar) * K + ac;
    const T*     Bp = Bw + (size_t)br * N + bn * 64 + bc;

    float acc[4][4] = {};

    for (int k0 = 0; k0 < K; k0 += 16) {
        float4 av = *(const float4*)(Ap + k0);
        As[ar][ac + 0] = av.x; As[ar][ac + 1] = av.y;
        As[ar][ac + 2] = av.z; As[ar][ac + 3] = av.w;
        float4 bv = ld4(Bp + (size_t)k0 * N);
        Bs[br][bc + 0] = bv.x; Bs[br][bc + 1] = bv.y;
        Bs[br][bc + 2] = bv.z; Bs[br][bc + 3] = bv.w;
        __syncthreads();
        #pragma unroll
        for (int kk = 0; kk < 16; ++kk) {
            float a[4], b[4];
            #pragma unroll
            for (int i = 0; i < 4; ++i) a[i] = As[ty * 4 + i][kk];
            #pragma unroll
            for (int j = 0; j < 4; ++j) b[j] = Bs[kk][tx * 4 + j];
            #pragma unroll
            for (int i = 0; i < 4; ++i)
                #pragma unroll
                for (int j = 0; j < 4; ++j) acc[i][j] += a[i] * b[j];
        }
        __syncthreads();
    }
    #pragma unroll
    for (int i = 0; i < 4; ++i) {
        #pragma unroll
        for (int j = 0; j < 4; ++j) {
            size_t idx = (size_t)(bm * 64 + ty * 4 + i) * N + bn * 64 + tx * 4 + j;
            float c = acc[i][j];
            if (resid) c += ldf(resid + idx);
            CF[idx] = c;
        }
    }
}

// ---------------------------------------------------------------- RoPE (fp32, in place)
template<typename FT>
__global__ __launch_bounds__(256) void rope_kernel(const int* __restrict__ flag,
                                                   float* __restrict__ t,
                                                   const FT* __restrict__ fc,
                                                   const FT* __restrict__ fs,
                                                   int nheads, int npairs)
{
    if (*flag != dtid<FT>::v) return;
    int gid = blockIdx.x * 256 + threadIdx.x;
    if (gid >= npairs) return;
    int i    = gid & 63;            // HD/2 = 64
    int rest = gid >> 6;
    int h    = rest % nheads;
    int tok  = rest / nheads;
    int spos = tok & (S_ - 1);
    float c = ldf(fc + spos * 64 + i);
    float s = ldf(fs + spos * 64 + i);
    size_t base = ((size_t)tok * nheads + h) * HD_ + 2 * i;
    float t1 = t[base], t2 = t[base + 1];
    t[base]     = t1 * c - t2 * s;
    t[base + 1] = t1 * s + t2 * c;
}

// ---------------------------------------------------------------- fp32 -> bf16 cast
__global__ __launch_bounds__(256) void cast_kernel(const int* __restrict__ flag,
                                                   const float* __restrict__ src,
                                                   u16* __restrict__ dst, int n)
{
    if (*flag != DT_BF16) return;
    int i = blockIdx.x * 256 + threadIdx.x;
    if (i < n) dst[i] = f2bf(src[i]);
}

// --------------------------------------------- Flash causal attention (all fp32)
// One 64-lane wave per (b, h, qpos); q updated in place. Flag-gated so each
// dtype pipeline runs it exactly once at the right point in stream order.
__global__ __launch_bounds__(64) void attn_kernel(const int* __restrict__ flag,
                                                  int want,
                                                  float* __restrict__ q,
                                                  const float* __restrict__ k,
                                                  const float* __restrict__ v)
{
    if (*flag != want) return;
    int gid  = blockIdx.x;
    int qpos = gid & (S_ - 1);
    int bh   = gid >> 11;           // /S_
    int h    = bh & (NH_ - 1);
    int b    = bh >> 4;             // /NH_
    int kvh  = h >> 2;              // rep = NH/NKV = 4
    int lane = threadIdx.x;

    size_t qoff = ((size_t)(b * S_ + qpos) * NH_ + h) * HD_;
    float q0 = q[qoff + lane], q1 = q[qoff + lane + 64];
    const float* kb = k + (size_t)b * S_ * NKV_ * HD_ + kvh * HD_;
    const float* vb = v + (size_t)b * S_ * NKV_ * HD_ + kvh * HD_;

    float m = -1e30f, l = 0.f, o0 = 0.f, o1 = 0.f;
    const float scale = 0.08838834764831845f;   // 1/sqrt(128)

    for (int j = 0; j <= qpos; ++j) {
        const float* kr = kb + (size_t)j * (NKV_ * HD_);
        float s = q0 * kr[lane] + q1 * kr[lane + 64];
        #pragma unroll
        for (int off = 32; off > 0; off >>= 1) s += __shfl_xor(s, off);
        s *= scale;
        float mn    = fmaxf(m, s);
        float alpha = __expf(m - mn);
        float p     = __expf(s - mn);
        const float* vr = vb + (size_t)j * (NKV_ * HD_);
        l  = l  * alpha + p;
        o0 = o0 * alpha + p * vr[lane];
        o1 = o1 * alpha + p * vr[lane + 64];
        m = mn;
    }
    float invl = 1.f / l;
    q[qoff + lane]      = o0 * invl;
    q[qoff + lane + 64] = o1 * invl;
}

// ---------------------------------------------------------------- top-2 gate
template<typename T>
__global__ __launch_bounds__(64) void gate_kernel(const int* __restrict__ flag,
                                                  const float* __restrict__ xt,
                                                  const T* __restrict__ gw,
                                                  int* __restrict__ eidx,
                                                  float* __restrict__ egw)
{
    if (*flag != dtid<T>::v) return;
    int t = blockIdx.x, lane = threadIdx.x;
    float acc[NE_] = {};
    const float* xr = xt + (size_t)t * DIM_;
    for (int d = lane; d < DIM_; d += 64) {
        float xd = xr[d];
        #pragma unroll
        for (int e = 0; e < NE_; ++e) acc[e] += xd * ldf(gw + d * NE_ + e);
    }
    #pragma unroll
    for (int e = 0; e < NE_; ++e)
        #pragma unroll
        for (int off = 32; off > 0; off >>= 1) acc[e] += __shfl_xor(acc[e], off);
    if (lane == 0) {
        // NaN-safe argmax pair: indices ALWAYS valid in [0, NE).
        int i0 = 0; float m0 = acc[0];
        #pragma unroll
        for (int e = 1; e < NE_; ++e) if (acc[e] > m0) { m0 = acc[e]; i0 = e; }
        int i1 = (i0 == 0) ? 1 : 0; float m1 = acc[i1];
        for (int e = i1 + 1; e < NE_; ++e)
            if (e != i0 && acc[e] > m1) { m1 = acc[e]; i1 = e; }
        float e1  = __expf(m1 - m0);
        float inv = 1.f / (1.f + e1);
        eidx[t * 2] = i0; eidx[t * 2 + 1] = i1;
        egw [t * 2] = inv; egw [t * 2 + 1] = e1 * inv;
    }
}

// ------------------------------------- MoE: one block per token (2 routed + shared).
// fp32 activations; weights dtype T; fuses x1 residual; writes final output.
template<typename T>
__global__ __launch_bounds__(256) void moe_kernel(const int* __restrict__ flag,
                                                  const float* __restrict__ h2,
                                                  const float* __restrict__ x1,
                                                  const T* __restrict__ w1,
                                                  const T* __restrict__ w2,
                                                  const T* __restrict__ w3,
                                                  const T* __restrict__ sw1,
                                                  const T* __restrict__ sw2,
                                                  const T* __restrict__ sw3,
                                                  const int* __restrict__ eidx,
                                                  const float* __restrict__ egw,
                                                  T* __restrict__ out)
{
    if (*flag != dtid<T>::v) return;
    int t = blockIdx.x;
    int j = threadIdx.x;
    __shared__ float sx[DIM_];
    __shared__ float she[HID_];
    for (int d = j; d < DIM_; d += 256)
        sx[d] = h2[(size_t)t * DIM_ + d];
    __syncthreads();

    float y[8] = {};
    for (int pass = 0; pass < 3; ++pass) {
        const T *W1, *W2, *W3; float g;
        if (pass < 2) {
            int e = eidx[t * 2 + pass] & 7;     // clamped: cannot go OOB
            g = egw[t * 2 + pass];
            W1 = w1 + (size_t)e * DIM_ * HID_;
            W3 = w3 + (size_t)e * DIM_ * HID_;
            W2 = w2 + (size_t)e * HID_ * DIM_;
        } else {
            W1 = sw1; W3 = sw3; W2 = sw2; g = 1.f;
        }
        float a1[4] = {}, a3[4] = {};
        for (int d = 0; d < DIM_; ++d) {
            float xd = sx[d];
            const T* r1 = W1 + (size_t)d * HID_;
            const T* r3 = W3 + (size_t)d * HID_;
            #pragma unroll
            for (int i = 0; i < 4; ++i) {
                a1[i] += xd * ldf(r1 + j + 256 * i);
                a3[i] += xd * ldf(r3 + j + 256 * i);
            }
        }
        #pragma unroll
        for (int i = 0; i < 4; ++i) {
            float h1 = a1[i];
            float sg = h1 / (1.f + __expf(-h1));   // silu
            she[j + 256 * i] = g * sg * a3[i];     // fold gate weight
        }
        __syncthreads();
        for (int hh = 0; hh < HID_; ++hh) {
            float hv = she[hh];
            const T* r2 = W2 + (size_t)hh * DIM_;
            #pragma unroll
            for (int i = 0; i < 8; ++i) y[i] += hv * ldf(r2 + j + 256 * i);
        }
        __syncthreads();   // she reused next pass
    }
    #pragma unroll
    for (int i = 0; i < 8; ++i) {
        size_t idx = (size_t)t * DIM_ + j + 256 * i;
        stf(out + idx, y[i] + x1[idx]);
    }
}

// ================================================================ launch
extern "C" void kernel_launch(void* const* d_in, const int* in_sizes, int n_in,
                              void* d_out, int out_size, void* d_ws, size_t ws_size,
                              hipStream_t stream)
{
    const size_t TD  = (size_t)T_ * DIM_;            // 8.4M elems
    const size_t TKV = (size_t)T_ * NKV_ * HD_;      // 2.1M elems

    char* ws = (char*)d_ws;
    int*   flag = (int*)ws;   ws += 16;
    int*   eidx = (int*)ws;   ws += (size_t)T_ * 2 * 4;
    float* egw  = (float*)ws; ws += (size_t)T_ * 2 * 4;
    float* bufA = (float*)ws; ws += TD * 4;          // h, later x1
    float* bufB = (float*)ws; ws += TD * 4;          // q/attn-out, later h2
    // -- fp32-external path stops here (~67.2 MiB) --
    float* bufKV = (float*)ws; ws += 2 * TKV * 4;    // k,v fp32 staging (bf16-ext only)

    detect_kernel<<<1, 1, 0, stream>>>((const unsigned int*)d_in[1], flag);

    dim3 gq(DIM_ / 64, T_ / 64);
    dim3 gkv((NKV_ * HD_) / 64, T_ / 64);
    int qpairs = T_ * NH_ * (HD_ / 2);
    int kpairs = T_ * NKV_ * (HD_ / 2);

    // Launch both dtype variants; every kernel self-gates on the flag.
    #define FOR_DTYPE(T)                                                          \
    {                                                                             \
        const T* x      = (const T*)d_in[0];                                      \
        const T* fcos   = (const T*)d_in[1];                                      \
        const T* fsin   = (const T*)d_in[2];                                      \
        const T* attn_w = (const T*)d_in[3];                                      \
        const T* ffn_w  = (const T*)d_in[4];                                      \
        const T* wq     = (const T*)d_in[5];                                      \
        const T* wk     = (const T*)d_in[6];                                      \
        const T* wv     = (const T*)d_in[7];                                      \
        const T* wo     = (const T*)d_in[8];                                      \
        const T* gate_w = (const T*)d_in[9];                                      \
        const T* w1     = (const T*)d_in[10];                                     \
        const T* w2     = (const T*)d_in[11];                                     \
        const T* w3     = (const T*)d_in[12];                                     \
        const T* sw1    = (const T*)d_in[13];                                     \
        const T* sw2    = (const T*)d_in[14];                                     \
        const T* sw3    = (const T*)d_in[15];                                     \
        T* out_x = (T*)d_out;                                                     \
        T* out_k = out_x + TD;                                                    \
        T* out_v = out_k + TKV;                                                   \
        const bool isF32 = (dtid<T>::v == DT_F32);                                \
        /* fp32 k/v live in d_out when external is fp32, else in ws staging */    \
        float* kf = isF32 ? (float*)out_k : bufKV;                                \
        float* vf = isF32 ? (float*)out_v : bufKV + TKV;                          \
        /* 1. h = rmsnorm(x) */                                                   \
        rmsnorm_kernel<T, T><<<T_, 256, 0, stream>>>(flag, x, attn_w, bufA);      \
        /* 2-4. q/k/v projections (fp32 outputs) */                               \
        gemm_kernel<T><<<gq,  256, 0, stream>>>(flag, bufA, wq, bufB,             \
                                                (const T*)nullptr, T_, DIM_, DIM_);\
        gemm_kernel<T><<<gkv, 256, 0, stream>>>(flag, bufA, wk, kf,               \
                                                (const T*)nullptr,                \
                                                T_, NKV_ * HD_, DIM_);            \
        gemm_kernel<T><<<gkv, 256, 0, stream>>>(flag, bufA, wv, vf,               \
                                                (const T*)nullptr,                \
                                                T_, NKV_ * HD_, DIM_);            \
        /* 5-6. RoPE in place (fp32) */                                           \
        rope_kernel<T><<<(qpairs + 255) / 256, 256, 0, stream>>>(                 \
            flag, bufB, fcos, fsin, NH_, qpairs);                                 \
        rope_kernel<T><<<(kpairs + 255) / 256, 256, 0, stream>>>(                 \
            flag, kf, fcos, fsin, NKV_, kpairs);                                  \
        /* bf16-external only: round k,v into d_out */                            \
        if (!isF32) {                                                             \
            cast_kernel<<<(int)((TKV + 255) / 256), 256, 0, stream>>>(            \
                flag, kf, (u16*)out_k, (int)TKV);                                 \
            cast_kernel<<<(int)((TKV + 255) / 256), 256, 0, stream>>>(            \
                flag, vf, (u16*)out_v, (int)TKV);                                 \
        }                                                                         \
        /* 7. attention (in place over q), flag-gated to this dtype */            \
        attn_kernel<<<B_ * NH_ * S_, 64, 0, stream>>>(flag, dtid<T>::v,           \
                                                      bufB, kf, vf);              \
        /* 8. x1 = x + attn @ wo  (bufA dead -> x1) */                            \
        gemm_kernel<T><<<gq, 256, 0, stream>>>(flag, bufB, wo, bufA, x,           \
                                               T_, DIM_, DIM_);                   \
        /* 9. h2 = rmsnorm(x1)  (bufB dead -> h2) */                              \
        rmsnorm_kernel<float, T><<<T_, 256, 0, stream>>>(flag, bufA, ffn_w, bufB);\
        /* 10. gate */                                                            \
        gate_kernel<T><<<T_, 64, 0, stream>>>(flag, bufB, gate_w, eidx, egw);     \
        /* 11. MoE + residual -> out_x */                                         \
        moe_kernel<T><<<T_, 256, 0, stream>>>(flag, bufB, bufA, w1, w2, w3,       \
                                              sw1, sw2, sw3, eidx, egw, out_x);   \
    }

    FOR_DTYPE(float)
    FOR_DTYPE(u16)
    #undef FOR_DTYPE
}

// Round 5
// 7472.699 us; speedup vs baseline: 5.4281x; 5.4281x over previous
//
#include <hip/hip_runtime.h>
#include <hip/hip_bf16.h>

// PK1Block: B=2 S=2048 DIM=2048 NH=16 NKV=4 HD=128 NE=8 TOPK=2 HID=SHID=1024
// External dtype: fp32 (confirmed R4). Pre-gate chain stays pure fp32 (routing
// is sensitive to ~0.003 logit noise). Post-gate MoE = expert-grouped bf16
// MFMA GEMMs (R4 evidence: per-token MoE re-read weights -> 129 GB HBM, 34 ms).
#define B_    2
#define S_    2048
#define DIM_  2048
#define NH_   16
#define NKV_  4
#define HD_   128
#define NE_   8
#define HID_  1024
#define T_    (B_*S_)          // 4096 tokens

typedef unsigned short u16;
typedef unsigned int   u32;

#define DT_BF16 1
#define DT_F32  2

template<typename T> struct dtid;
template<> struct dtid<float> { static constexpr int v = DT_F32;  };
template<> struct dtid<u16>   { static constexpr int v = DT_BF16; };

typedef __attribute__((ext_vector_type(8))) short short8;   // 8 x bf16
typedef __attribute__((ext_vector_type(4))) float f32x4;

__device__ __forceinline__ float u2f(u16 u) {
    union { u32 i; float f; } v; v.i = ((u32)u) << 16; return v.f;
}
__device__ __forceinline__ u16 f2bf(float f) {
    union { float f; u32 i; } v; v.f = f;
    u32 x = v.i;
    return (u16)((x + 0x7fffu + ((x >> 16) & 1u)) >> 16);   // RNE
}
__device__ __forceinline__ u32 pack2(float lo, float hi) {
    return (u32)f2bf(lo) | ((u32)f2bf(hi) << 16);
}

template<typename T> __device__ __forceinline__ float ldf(const T* p);
template<> __device__ __forceinline__ float ldf<float>(const float* p) { return *p; }
template<> __device__ __forceinline__ float ldf<u16>(const u16* p)     { return u2f(*p); }

template<typename T> __device__ __forceinline__ void stf(T* p, float v);
template<> __device__ __forceinline__ void stf<float>(float* p, float v) { *p = v; }
template<> __device__ __forceinline__ void stf<u16>(u16* p, float v)     { *p = f2bf(v); }

template<typename T> __device__ __forceinline__ float4 ld4(const T* p);
template<> __device__ __forceinline__ float4 ld4<float>(const float* p) {
    return *(const float4*)p;
}
template<> __device__ __forceinline__ float4 ld4<u16>(const u16* p) {
    ushort4 q = *(const ushort4*)p;
    return make_float4(u2f(q.x), u2f(q.y), u2f(q.z), u2f(q.w));
}

// ---------------------------------------------------------------- dtype detect
__global__ void detect_kernel(const u32* __restrict__ fcos_words,
                              int* __restrict__ flag)
{
    *flag = (fcos_words[0] == 0x3F800000u) ? DT_F32 : DT_BF16;
}

__global__ void init_kernel(int* __restrict__ counts)   // counts[16]+cursor[16]
{
    if (threadIdx.x < 32) counts[threadIdx.x] = 0;
}

// ------------------------------------------------- RMSNorm: IT in -> fp32 out
template<typename IT, typename WT>
__global__ __launch_bounds__(256) void rmsnorm_kernel(const int* __restrict__ flag,
                                                      const IT* __restrict__ xin,
                                                      const WT* __restrict__ w,
                                                      float* __restrict__ out)
{
    if (*flag != dtid<WT>::v) return;
    int t = blockIdx.x;
    const IT* xb = xin + (size_t)t * DIM_;
    float ss = 0.f;
    for (int d = threadIdx.x; d < DIM_; d += 256) {
        float v = ldf(xb + d);
        ss += v * v;
    }
    #pragma unroll
    for (int o = 32; o > 0; o >>= 1) ss += __shfl_xor(ss, o);
    __shared__ float red[4];
    if ((threadIdx.x & 63) == 0) red[threadIdx.x >> 6] = ss;
    __syncthreads();
    float tot = red[0] + red[1] + red[2] + red[3];
    float inv = rsqrtf(tot * (1.0f / DIM_) + 1e-6f);
    for (int d = threadIdx.x; d < DIM_; d += 256)
        out[(size_t)t * DIM_ + d] = ldf(xb + d) * inv * ldf(w + d);
}

// ---------------------- GEMM: A(fp32 ws) @ B(T) -> CF(fp32) [+resid(T)]
template<typename T>
__global__ __launch_bounds__(256) void gemm_kernel(const int* __restrict__ flag,
                                                   const float* __restrict__ A,
                                                   const T* __restrict__ Bw,
                                                   float* __restrict__ CF,
                                                   const T* __restrict__ resid,
                                                   int M, int N, int K)
{
    if (*flag != dtid<T>::v) return;
    __shared__ float As[64][17];
    __shared__ float Bs[16][64];
    int tid = threadIdx.x;
    int bm = blockIdx.y, bn = blockIdx.x;
    int tx = tid & 15, ty = tid >> 4;

    int ar = tid >> 2;
    int ac = (tid & 3) << 2;
    int br = tid >> 4;
    int bc = (tid & 15) << 2;

    const float* Ap = A  + (size_t)(bm * 64 + ar) * K + ac;
    const T*     Bp = Bw + (size_t)br * N + bn * 64 + bc;

    float acc[4][4] = {};

    for (int k0 = 0; k0 < K; k0 += 16) {
        float4 av = *(const float4*)(Ap + k0);
        As[ar][ac + 0] = av.x; As[ar][ac + 1] = av.y;
        As[ar][ac + 2] = av.z; As[ar][ac + 3] = av.w;
        float4 bv = ld4(Bp + (size_t)k0 * N);
        Bs[br][bc + 0] = bv.x; Bs[br][bc + 1] = bv.y;
        Bs[br][bc + 2] = bv.z; Bs[br][bc + 3] = bv.w;
        __syncthreads();
        #pragma unroll
        for (int kk = 0; kk < 16; ++kk) {
            float a[4], b[4];
            #pragma unroll
            for (int i = 0; i < 4; ++i) a[i] = As[ty * 4 + i][kk];
            #pragma unroll
            for (int j = 0; j < 4; ++j) b[j] = Bs[kk][tx * 4 + j];
            #pragma unroll
            for (int i = 0; i < 4; ++i)
                #pragma unroll
                for (int j = 0; j < 4; ++j) acc[i][j] += a[i] * b[j];
        }
        __syncthreads();
    }
    #pragma unroll
    for (int i = 0; i < 4; ++i) {
        #pragma unroll
        for (int j = 0; j < 4; ++j) {
            size_t idx = (size_t)(bm * 64 + ty * 4 + i) * N + bn * 64 + tx * 4 + j;
            float c = acc[i][j];
            if (resid) c += ldf(resid + idx);
            CF[idx] = c;
        }
    }
}

// ---------------------------------------------------------------- RoPE (fp32, in place)
template<typename FT>
__global__ __launch_bounds__(256) void rope_kernel(const int* __restrict__ flag,
                                                   float* __restrict__ t,
                                                   const FT* __restrict__ fc,
                                                   const FT* __restrict__ fs,
                                                   int nheads, int npairs)
{
    if (*flag != dtid<FT>::v) return;
    int gid = blockIdx.x * 256 + threadIdx.x;
    if (gid >= npairs) return;
    int i    = gid & 63;
    int rest = gid >> 6;
    int h    = rest % nheads;
    int tok  = rest / nheads;
    int spos = tok & (S_ - 1);
    float c = ldf(fc + spos * 64 + i);
    float s = ldf(fs + spos * 64 + i);
    size_t base = ((size_t)tok * nheads + h) * HD_ + 2 * i;
    float t1 = t[base], t2 = t[base + 1];
    t[base]     = t1 * c - t2 * s;
    t[base + 1] = t1 * s + t2 * c;
}

// ---------------------------------------------------------------- fp32 -> bf16 cast
__global__ __launch_bounds__(256) void cast_kernel(const int* __restrict__ flag,
                                                   const float* __restrict__ src,
                                                   u16* __restrict__ dst, int n)
{
    if (*flag != DT_BF16) return;
    int i = blockIdx.x * 256 + threadIdx.x;
    if (i < n) dst[i] = f2bf(src[i]);
}

// --------------------------------------------- Flash causal attention (fp32)
__global__ __launch_bounds__(64) void attn_kernel(const int* __restrict__ flag,
                                                  int want,
                                                  float* __restrict__ q,
                                                  const float* __restrict__ k,
                                                  const float* __restrict__ v)
{
    if (*flag != want) return;
    int gid  = blockIdx.x;
    int qpos = gid & (S_ - 1);
    int bh   = gid >> 11;
    int h    = bh & (NH_ - 1);
    int b    = bh >> 4;
    int kvh  = h >> 2;
    int lane = threadIdx.x;

    size_t qoff = ((size_t)(b * S_ + qpos) * NH_ + h) * HD_;
    float q0 = q[qoff + lane], q1 = q[qoff + lane + 64];
    const float* kb = k + (size_t)b * S_ * NKV_ * HD_ + kvh * HD_;
    const float* vb = v + (size_t)b * S_ * NKV_ * HD_ + kvh * HD_;

    float m = -1e30f, l = 0.f, o0 = 0.f, o1 = 0.f;
    const float scale = 0.08838834764831845f;

    for (int j = 0; j <= qpos; ++j) {
        const float* kr = kb + (size_t)j * (NKV_ * HD_);
        float s = q0 * kr[lane] + q1 * kr[lane + 64];
        #pragma unroll
        for (int off = 32; off > 0; off >>= 1) s += __shfl_xor(s, off);
        s *= scale;
        float mn    = fmaxf(m, s);
        float alpha = __expf(m - mn);
        float p     = __expf(s - mn);
        const float* vr = vb + (size_t)j * (NKV_ * HD_);
        l  = l  * alpha + p;
        o0 = o0 * alpha + p * vr[lane];
        o1 = o1 * alpha + p * vr[lane + 64];
        m = mn;
    }
    float invl = 1.f / l;
    q[qoff + lane]      = o0 * invl;
    q[qoff + lane + 64] = o1 * invl;
}

// ---------------------------------------------------------------- top-2 gate
template<typename T>
__global__ __launch_bounds__(64) void gate_kernel(const int* __restrict__ flag,
                                                  const float* __restrict__ xt,
                                                  const T* __restrict__ gw,
                                                  int* __restrict__ eidx,
                                                  float* __restrict__ egw,
                                                  int* __restrict__ counts)
{
    if (*flag != dtid<T>::v) return;
    int t = blockIdx.x, lane = threadIdx.x;
    float acc[NE_] = {};
    const float* xr = xt + (size_t)t * DIM_;
    for (int d = lane; d < DIM_; d += 64) {
        float xd = xr[d];
        #pragma unroll
        for (int e = 0; e < NE_; ++e) acc[e] += xd * ldf(gw + d * NE_ + e);
    }
    #pragma unroll
    for (int e = 0; e < NE_; ++e)
        #pragma unroll
        for (int off = 32; off > 0; off >>= 1) acc[e] += __shfl_xor(acc[e], off);
    if (lane == 0) {
        int i0 = 0; float m0 = acc[0];
        #pragma unroll
        for (int e = 1; e < NE_; ++e) if (acc[e] > m0) { m0 = acc[e]; i0 = e; }
        int i1 = (i0 == 0) ? 1 : 0; float m1 = acc[i1];
        for (int e = i1 + 1; e < NE_; ++e)
            if (e != i0 && acc[e] > m1) { m1 = acc[e]; i1 = e; }
        float e1  = __expf(m1 - m0);
        float inv = 1.f / (1.f + e1);
        eidx[t * 2] = i0; eidx[t * 2 + 1] = i1;
        egw [t * 2] = inv; egw [t * 2 + 1] = e1 * inv;
        atomicAdd(&counts[i0], 1);
        atomicAdd(&counts[i1], 1);
    }
}

__global__ void offs_kernel(const int* __restrict__ counts, int* __restrict__ offs)
{
    if (threadIdx.x == 0) {
        int off = 0;
        for (int e = 0; e < NE_; ++e) { offs[e] = off; off += counts[e]; }
    }
}

__global__ __launch_bounds__(256) void scatter_kernel(const int* __restrict__ eidx,
                                                      const int* __restrict__ offs,
                                                      int* __restrict__ cursor,
                                                      int* __restrict__ list)
{
    int s = blockIdx.x * 256 + threadIdx.x;
    if (s >= T_ * 2) return;
    int e = eidx[s] & 7;
    int pos = atomicAdd(&cursor[e], 1);
    list[offs[e] + pos] = s;
}

// ------------------- MoE phase A: he = silu(X@W1) * (X@W3), bf16 MFMA
// grid (HID/128, 128, 9). e==8 -> shared expert over all tokens.
__global__ __launch_bounds__(256) void moe_h_kernel(const int* __restrict__ flag,
                                                    const float* __restrict__ h2,
                                                    const float* __restrict__ w1,
                                                    const float* __restrict__ w3,
                                                    const float* __restrict__ sw1,
                                                    const float* __restrict__ sw3,
                                                    const int* __restrict__ list,
                                                    const int* __restrict__ counts,
                                                    const int* __restrict__ offs,
                                                    u16* __restrict__ he)
{
    if (*flag != DT_F32) return;
    int e   = blockIdx.z;
    int cnt = (e < 8) ? counts[e] : T_;
    int my0 = blockIdx.y * 64;
    if (my0 >= cnt) return;
    int n0   = blockIdx.x * 128;
    int base = ((e < 8) ? offs[e] : 2 * T_) + my0;   // he entry base
    const float* W1 = (e < 8) ? w1 + (size_t)e * DIM_ * HID_ : sw1;
    const float* W3 = (e < 8) ? w3 + (size_t)e * DIM_ * HID_ : sw3;

    __shared__ int toks[64];
    __shared__ u16 Bs[2][128 * 40];   // [n][k] bf16, pitch 40 (16B-aligned rows)

    int t = threadIdx.x;
    if (t < 64) {
        int m  = my0 + t;
        int mm = m < cnt ? m : cnt - 1;
        toks[t] = (e < 8) ? (list[((e < 8) ? offs[e] : 0) + mm] >> 1) : mm;
    }
    __syncthreads();

    int wave = t >> 6, lane = t & 63;
    int q = lane >> 4, l16 = lane & 15;
    int mytok = toks[wave * 16 + l16];          // A-row token for this lane
    const float* arow = h2 + (size_t)mytok * DIM_;

    int kp = t & 15;        // k-pair 0..15  (k = 2*kp, 2*kp+1)
    int ng = t >> 4;        // n-group 0..15 (n = 8*ng .. +8)

    f32x4 acc[2][8];
    #pragma unroll
    for (int m_ = 0; m_ < 2; ++m_)
        #pragma unroll
        for (int nt = 0; nt < 8; ++nt) acc[m_][nt] = (f32x4){0.f, 0.f, 0.f, 0.f};

    for (int d0 = 0; d0 < DIM_; d0 += 32) {
        __syncthreads();
        // stage W1, W3 tiles transposed into Bs[n][k]
        #pragma unroll
        for (int mat = 0; mat < 2; ++mat) {
            const float* W = (mat ? W3 : W1) + (size_t)(d0 + 2 * kp) * HID_ + n0 + 8 * ng;
            float4 a0 = *(const float4*)(W);
            float4 a1 = *(const float4*)(W + 4);
            float4 b0 = *(const float4*)(W + HID_);
            float4 b1 = *(const float4*)(W + HID_ + 4);
            u32* dst = (u32*)Bs[mat] + kp;
            dst[(8 * ng + 0) * 20] = pack2(a0.x, b0.x);
            dst[(8 * ng + 1) * 20] = pack2(a0.y, b0.y);
            dst[(8 * ng + 2) * 20] = pack2(a0.z, b0.z);
            dst[(8 * ng + 3) * 20] = pack2(a0.w, b0.w);
            dst[(8 * ng + 4) * 20] = pack2(a1.x, b1.x);
            dst[(8 * ng + 5) * 20] = pack2(a1.y, b1.y);
            dst[(8 * ng + 6) * 20] = pack2(a1.z, b1.z);
            dst[(8 * ng + 7) * 20] = pack2(a1.w, b1.w);
        }
        __syncthreads();
        // A fragment direct from global (fp32 -> bf16)
        const float* ap = arow + d0 + q * 8;
        float4 af0 = *(const float4*)(ap);
        float4 af1 = *(const float4*)(ap + 4);
        short8 afr;
        afr[0] = (short)f2bf(af0.x); afr[1] = (short)f2bf(af0.y);
        afr[2] = (short)f2bf(af0.z); afr[3] = (short)f2bf(af0.w);
        afr[4] = (short)f2bf(af1.x); afr[5] = (short)f2bf(af1.y);
        afr[6] = (short)f2bf(af1.z); afr[7] = (short)f2bf(af1.w);
        #pragma unroll
        for (int nt = 0; nt < 8; ++nt) {
            short8 b1f = *(const short8*)&Bs[0][(nt * 16 + l16) * 40 + q * 8];
            acc[0][nt] = __builtin_amdgcn_mfma_f32_16x16x32_bf16(afr, b1f, acc[0][nt], 0, 0, 0);
            short8 b3f = *(const short8*)&Bs[1][(nt * 16 + l16) * 40 + q * 8];
            acc[1][nt] = __builtin_amdgcn_mfma_f32_16x16x32_bf16(afr, b3f, acc[1][nt], 0, 0, 0);
        }
    }
    // epilogue: he = silu(h1) * h3  (D layout: col=l16, row=q*4+r)
    #pragma unroll
    for (int nt = 0; nt < 8; ++nt) {
        #pragma unroll
        for (int r = 0; r < 4; ++r) {
            int mrow = wave * 16 + q * 4 + r;
            if (my0 + mrow < cnt) {
                float h1 = acc[0][nt][r];
                float h3 = acc[1][nt][r];
                float v  = (h1 / (1.f + __expf(-h1))) * h3;
                he[(size_t)(base + mrow) * HID_ + n0 + nt * 16 + l16] = f2bf(v);
            }
        }
    }
}

// ------------------- MoE phase B: out += g * (he @ W2), bf16 MFMA + f32 atomics
// grid (DIM/128, 128, 9)
__global__ __launch_bounds__(256) void moe_y_kernel(const int* __restrict__ flag,
                                                    const u16* __restrict__ he,
                                                    const float* __restrict__ w2,
                                                    const float* __restrict__ sw2,
                                                    const int* __restrict__ list,
                                                    const int* __restrict__ counts,
                                                    const int* __restrict__ offs,
                                                    const float* __restrict__ egw,
                                                    float* __restrict__ out)
{
    if (*flag != DT_F32) return;
    int e   = blockIdx.z;
    int cnt = (e < 8) ? counts[e] : T_;
    int my0 = blockIdx.y * 64;
    if (my0 >= cnt) return;
    int d0   = blockIdx.x * 128;
    int base = ((e < 8) ? offs[e] : 2 * T_) + my0;
    const float* W2 = (e < 8) ? w2 + (size_t)e * HID_ * DIM_ : sw2;

    __shared__ int   stok[64];
    __shared__ float sg[64];
    __shared__ u16   Bs[128 * 40];

    int t = threadIdx.x;
    if (t < 64) {
        int m  = my0 + t;
        int mm = m < cnt ? m : cnt - 1;
        if (e < 8) {
            int s = list[offs[e] + mm];
            stok[t] = s >> 1; sg[t] = egw[s];
        } else {
            stok[t] = mm; sg[t] = 1.f;
        }
    }
    __syncthreads();

    int wave = t >> 6, lane = t & 63;
    int q = lane >> 4, l16 = lane & 15;
    const u16* arow = he + (size_t)(base + wave * 16 + l16) * HID_;

    int kp = t & 15;
    int ng = t >> 4;

    f32x4 acc[8];
    #pragma unroll
    for (int nt = 0; nt < 8; ++nt) acc[nt] = (f32x4){0.f, 0.f, 0.f, 0.f};

    for (int h0 = 0; h0 < HID_; h0 += 32) {
        __syncthreads();
        const float* W = W2 + (size_t)(h0 + 2 * kp) * DIM_ + d0 + 8 * ng;
        float4 a0 = *(const float4*)(W);
        float4 a1 = *(const float4*)(W + 4);
        float4 b0 = *(const float4*)(W + DIM_);
        float4 b1 = *(const float4*)(W + DIM_ + 4);
        u32* dst = (u32*)Bs + kp;
        dst[(8 * ng + 0) * 20] = pack2(a0.x, b0.x);
        dst[(8 * ng + 1) * 20] = pack2(a0.y, b0.y);
        dst[(8 * ng + 2) * 20] = pack2(a0.z, b0.z);
        dst[(8 * ng + 3) * 20] = pack2(a0.w, b0.w);
        dst[(8 * ng + 4) * 20] = pack2(a1.x, b1.x);
        dst[(8 * ng + 5) * 20] = pack2(a1.y, b1.y);
        dst[(8 * ng + 6) * 20] = pack2(a1.z, b1.z);
        dst[(8 * ng + 7) * 20] = pack2(a1.w, b1.w);
        __syncthreads();
        short8 afr = *(const short8*)(arow + h0 + q * 8);
        #pragma unroll
        for (int nt = 0; nt < 8; ++nt) {
            short8 bf = *(const short8*)&Bs[(nt * 16 + l16) * 40 + q * 8];
            acc[nt] = __builtin_amdgcn_mfma_f32_16x16x32_bf16(afr, bf, acc[nt], 0, 0, 0);
        }
    }
    #pragma unroll
    for (int r = 0; r < 4; ++r) {
        int mrow = wave * 16 + q * 4 + r;
        if (my0 + mrow < cnt) {
            int   tok = stok[mrow];
            float g   = sg[mrow];
            float* orow = out + (size_t)tok * DIM_ + d0 + l16;
            #pragma unroll
            for (int nt = 0; nt < 8; ++nt)
                unsafeAtomicAdd(orow + nt * 16, g * acc[nt][r]);
        }
    }
}

// --------------- old per-token MoE: bf16-external insurance path only
template<typename T>
__global__ __launch_bounds__(256) void moe_kernel(const int* __restrict__ flag,
                                                  const float* __restrict__ h2,
                                                  const float* __restrict__ x1,
                                                  const T* __restrict__ w1,
                                                  const T* __restrict__ w2,
                                                  const T* __restrict__ w3,
                                                  const T* __restrict__ sw1,
                                                  const T* __restrict__ sw2,
                                                  const T* __restrict__ sw3,
                                                  const int* __restrict__ eidx,
                                                  const float* __restrict__ egw,
                                                  T* __restrict__ out)
{
    if (*flag != dtid<T>::v) return;
    int t = blockIdx.x;
    int j = threadIdx.x;
    __shared__ float sx[DIM_];
    __shared__ float she[HID_];
    for (int d = j; d < DIM_; d += 256)
        sx[d] = h2[(size_t)t * DIM_ + d];
    __syncthreads();

    float y[8] = {};
    for (int pass = 0; pass < 3; ++pass) {
        const T *W1, *W2, *W3; float g;
        if (pass < 2) {
            int e = eidx[t * 2 + pass] & 7;
            g = egw[t * 2 + pass];
            W1 = w1 + (size_t)e * DIM_ * HID_;
            W3 = w3 + (size_t)e * DIM_ * HID_;
            W2 = w2 + (size_t)e * HID_ * DIM_;
        } else {
            W1 = sw1; W3 = sw3; W2 = sw2; g = 1.f;
        }
        float a1[4] = {}, a3[4] = {};
        for (int d = 0; d < DIM_; ++d) {
            float xd = sx[d];
            const T* r1 = W1 + (size_t)d * HID_;
            const T* r3 = W3 + (size_t)d * HID_;
            #pragma unroll
            for (int i = 0; i < 4; ++i) {
                a1[i] += xd * ldf(r1 + j + 256 * i);
                a3[i] += xd * ldf(r3 + j + 256 * i);
            }
        }
        #pragma unroll
        for (int i = 0; i < 4; ++i) {
            float h1 = a1[i];
            she[j + 256 * i] = g * (h1 / (1.f + __expf(-h1))) * a3[i];
        }
        __syncthreads();
        for (int hh = 0; hh < HID_; ++hh) {
            float hv = she[hh];
            const T* r2 = W2 + (size_t)hh * DIM_;
            #pragma unroll
            for (int i = 0; i < 8; ++i) y[i] += hv * ldf(r2 + j + 256 * i);
        }
        __syncthreads();
    }
    #pragma unroll
    for (int i = 0; i < 8; ++i) {
        size_t idx = (size_t)t * DIM_ + j + 256 * i;
        stf(out + idx, y[i] + x1[idx]);
    }
}

// ================================================================ launch
extern "C" void kernel_launch(void* const* d_in, const int* in_sizes, int n_in,
                              void* d_out, int out_size, void* d_ws, size_t ws_size,
                              hipStream_t stream)
{
    const size_t TD  = (size_t)T_ * DIM_;            // 8.4M elems
    const size_t TKV = (size_t)T_ * NKV_ * HD_;      // 2.1M elems

    char* ws = (char*)d_ws;
    int*   flag   = (int*)ws;   ws += 16;
    int*   counts = (int*)ws;   ws += 16 * 4;        // counts[16]
    int*   cursor = counts + 16;                     // (part of same 32-int block? no)
    ws += 16 * 4;                                    // cursor[16]
    int*   offs   = (int*)ws;   ws += 16 * 4;
    int*   eidx   = (int*)ws;   ws += (size_t)T_ * 2 * 4;
    float* egw    = (float*)ws; ws += (size_t)T_ * 2 * 4;
    int*   list   = (int*)ws;   ws += (size_t)T_ * 2 * 4;
    float* bufA   = (float*)ws; ws += TD * 4;        // h, then h2
    float* bufB   = (float*)ws; ws += TD * 4;        // q/attn-out; he overlaps after
    u16*   he     = (u16*)bufB;                      // 12288*1024 bf16 = 25.2MB <= 33.5MB
    // bf16-external-only staging (never touched in fp32 mode):
    float* bufKV  = (float*)ws; ws += 2 * TKV * 4;
    float* bufX1f = (float*)ws; ws += TD * 4;

    detect_kernel<<<1, 1, 0, stream>>>((const u32*)d_in[1], flag);
    init_kernel<<<1, 64, 0, stream>>>(counts);

    dim3 gq(DIM_ / 64, T_ / 64);
    dim3 gkv((NKV_ * HD_) / 64, T_ / 64);
    int qpairs = T_ * NH_ * (HD_ / 2);
    int kpairs = T_ * NKV_ * (HD_ / 2);

    #define FOR_DTYPE(T)                                                          \
    {                                                                             \
        const T* x      = (const T*)d_in[0];                                      \
        const T* fcos   = (const T*)d_in[1];                                      \
        const T* fsin   = (const T*)d_in[2];                                      \
        const T* attn_w = (const T*)d_in[3];                                      \
        const T* ffn_w  = (const T*)d_in[4];                                      \
        const T* wq     = (const T*)d_in[5];                                      \
        const T* wk     = (const T*)d_in[6];                                      \
        const T* wv     = (const T*)d_in[7];                                      \
        const T* wo     = (const T*)d_in[8];                                      \
        const T* gate_w = (const T*)d_in[9];                                      \
        T* out_x = (T*)d_out;                                                     \
        T* out_k = out_x + TD;                                                    \
        T* out_v = out_k + TKV;                                                   \
        const bool isF32 = (dtid<T>::v == DT_F32);                                \
        float* kf  = isF32 ? (float*)out_k : bufKV;                               \
        float* vf  = isF32 ? (float*)out_v : bufKV + TKV;                         \
        float* x1f = isF32 ? (float*)out_x : bufX1f;                              \
        rmsnorm_kernel<T, T><<<T_, 256, 0, stream>>>(flag, x, attn_w, bufA);      \
        gemm_kernel<T><<<gq,  256, 0, stream>>>(flag, bufA, wq, bufB,             \
                                                (const T*)nullptr, T_, DIM_, DIM_);\
        gemm_kernel<T><<<gkv, 256, 0, stream>>>(flag, bufA, wk, kf,               \
                                                (const T*)nullptr,                \
                                                T_, NKV_ * HD_, DIM_);            \
        gemm_kernel<T><<<gkv, 256, 0, stream>>>(flag, bufA, wv, vf,               \
                                                (const T*)nullptr,                \
                                                T_, NKV_ * HD_, DIM_);            \
        rope_kernel<T><<<(qpairs + 255) / 256, 256, 0, stream>>>(                 \
            flag, bufB, fcos, fsin, NH_, qpairs);                                 \
        rope_kernel<T><<<(kpairs + 255) / 256, 256, 0, stream>>>(                 \
            flag, kf, fcos, fsin, NKV_, kpairs);                                  \
        if (!isF32) {                                                             \
            cast_kernel<<<(int)((TKV + 255) / 256), 256, 0, stream>>>(            \
                flag, kf, (u16*)out_k, (int)TKV);                                 \
            cast_kernel<<<(int)((TKV + 255) / 256), 256, 0, stream>>>(            \
                flag, vf, (u16*)out_v, (int)TKV);                                 \
        }                                                                         \
        attn_kernel<<<B_ * NH_ * S_, 64, 0, stream>>>(flag, dtid<T>::v,           \
                                                      bufB, kf, vf);              \
        /* x1 = x + attn @ wo (fp32: straight into d_out) */                      \
        gemm_kernel<T><<<gq, 256, 0, stream>>>(flag, bufB, wo, x1f, x,            \
                                               T_, DIM_, DIM_);                   \
        /* h2 = rmsnorm(x1) -> bufA (bufA's h is dead) */                         \
        rmsnorm_kernel<float, T><<<T_, 256, 0, stream>>>(flag, x1f, ffn_w, bufA); \
        gate_kernel<T><<<T_, 64, 0, stream>>>(flag, bufA, gate_w, eidx, egw,      \
                                              counts);                            \
    }

    FOR_DTYPE(float)
    FOR_DTYPE(u16)
    #undef FOR_DTYPE

    // routing bookkeeping (valid for whichever gate ran)
    offs_kernel<<<1, 1, 0, stream>>>(counts, offs);
    scatter_kernel<<<(T_ * 2 + 255) / 256, 256, 0, stream>>>(eidx, offs, cursor, list);

    // fp32 path: grouped bf16-MFMA MoE, atomically accumulated onto x1 in d_out
    {
        const float* w1  = (const float*)d_in[10];
        const float* w2  = (const float*)d_in[11];
        const float* w3  = (const float*)d_in[12];
        const float* sw1 = (const float*)d_in[13];
        const float* sw2 = (const float*)d_in[14];
        const float* sw3 = (const float*)d_in[15];
        dim3 ga(HID_ / 128, 128, 9);
        dim3 gb(DIM_ / 128, 128, 9);
        moe_h_kernel<<<ga, 256, 0, stream>>>(flag, bufA, w1, w3, sw1, sw3,
                                             list, counts, offs, he);
        moe_y_kernel<<<gb, 256, 0, stream>>>(flag, he, w2, sw2,
                                             list, counts, offs, egw,
                                             (float*)d_out);
    }

    // bf16-external insurance path: per-token MoE with fused residual
    moe_kernel<u16><<<T_, 256, 0, stream>>>(flag, bufA, bufX1f,
                                            (const u16*)d_in[10], (const u16*)d_in[11],
                                            (const u16*)d_in[12], (const u16*)d_in[13],
                                            (const u16*)d_in[14], (const u16*)d_in[15],
                                            eidx, egw, (u16*)d_out);
}